// Round 2
// baseline (1082.501 us; speedup 1.0000x reference)
//
#include <hip/hip_runtime.h>

typedef __bf16 bf16;
typedef __bf16 bf16x8 __attribute__((ext_vector_type(8)));
typedef float f32x4 __attribute__((ext_vector_type(4)));

#define T_ 4
#define B_ 8
#define C_ 512
#define D_ 768
#define H_ 8
#define HL_ 2
#define HD_ 96
#define MKV_ 192
#define M2_ 4096            // B*C
#define BCD_ 3145728        // B*C*D
#define M3_ 16384           // T*B*C

// ---------------------------------------------------------------------------
// Kernel 1: xs = lif(x), fp64 scan (matches fp64 numpy reference decisions).
// x: fp32 (T,B,C,D) ; xs: bf16 spikes (exact 0/1)
// ---------------------------------------------------------------------------
__global__ __launch_bounds__(256) void lif_x_kernel(const float* __restrict__ x,
                                                    bf16* __restrict__ xs) {
    int i = blockIdx.x * blockDim.x + threadIdx.x;
    if (i >= BCD_) return;
    double v = 0.0;
    #pragma unroll
    for (int t = 0; t < T_; ++t) {
        v = v * 0.5 + (double)x[(size_t)t * BCD_ + i];
        float s = (v >= 1.0) ? 1.0f : 0.0f;
        xs[(size_t)t * BCD_ + i] = (bf16)s;
        if (s != 0.0f) v = 0.0;
    }
}

// ---------------------------------------------------------------------------
// Kernel 1b: split fp32 weight -> (hi, lo) bf16 pair.  w ~= hi + lo exactly
// to ~2^-18 relative.
// ---------------------------------------------------------------------------
__global__ __launch_bounds__(256) void split_w_kernel(const float* __restrict__ w,
                                                      bf16* __restrict__ hi,
                                                      bf16* __restrict__ lo, int n) {
    int i = blockIdx.x * blockDim.x + threadIdx.x;
    if (i >= n) return;
    float v = w[i];
    bf16 h = (bf16)v;
    hi[i] = h;
    lo[i] = (bf16)(v - (float)h);
}

__global__ __launch_bounds__(256) void cvt_w_kernel(const float* __restrict__ w,
                                                    bf16* __restrict__ o, int n) {
    int i = blockIdx.x * blockDim.x + threadIdx.x;
    if (i >= n) return;
    o[i] = (bf16)w[i];
}

// ---------------------------------------------------------------------------
// Kernel 2: spikes = lif(xs @ W^T), split-bf16 2-pass MFMA (fp32-accurate),
// fused LIF over T in regs; near-threshold (|v-1|<1e-4) trajectories redone
// in fp64 against the ORIGINAL fp32 weights.
//   xs: (T,M2,D) bf16 spikes ; Whi/Wlo: (N,D) bf16 ; Wf: (N,D) fp32
//   out: (T,M2,N) bf16 spikes
// ---------------------------------------------------------------------------
__global__ __launch_bounds__(256) void proj_lif_kernel(
    const bf16* __restrict__ xs, const bf16* __restrict__ Whi,
    const bf16* __restrict__ Wlo, const float* __restrict__ Wf,
    bf16* __restrict__ out, int N)
{
    const int wave = threadIdx.x >> 6;
    const int lane = threadIdx.x & 63;
    const int m16  = lane & 15;
    const int quad = lane >> 4;
    const int ntiles = N >> 5;
    const int gw   = blockIdx.x * 4 + wave;
    const int n0   = (gw % ntiles) * 32;
    const int m0   = (gw / ntiles) * 32;

    float vstate[2][2][4];
    #pragma unroll
    for (int a = 0; a < 2; a++)
        #pragma unroll
        for (int b = 0; b < 2; b++)
            #pragma unroll
            for (int r = 0; r < 4; r++) vstate[a][b][r] = 0.f;

    unsigned sbits[T_];
    unsigned flags = 0;

    for (int t = 0; t < T_; ++t) {
        f32x4 acch[2][2], accl[2][2];
        #pragma unroll
        for (int a = 0; a < 2; a++)
            #pragma unroll
            for (int b = 0; b < 2; b++) {
                f32x4 z = {0.f, 0.f, 0.f, 0.f};
                acch[a][b] = z; accl[a][b] = z;
            }
        const bf16* Abase  = xs  + ((size_t)(t * M2_ + m0 + m16)) * D_ + quad * 8;
        const bf16* Bhbase = Whi + ((size_t)(n0 + m16)) * D_ + quad * 8;
        const bf16* Blbase = Wlo + ((size_t)(n0 + m16)) * D_ + quad * 8;
        for (int k0 = 0; k0 < D_; k0 += 32) {
            bf16x8 a0 = *(const bf16x8*)(Abase + k0);
            bf16x8 a1 = *(const bf16x8*)(Abase + k0 + 16 * D_);
            bf16x8 bh0 = *(const bf16x8*)(Bhbase + k0);
            bf16x8 bh1 = *(const bf16x8*)(Bhbase + k0 + 16 * D_);
            bf16x8 bl0 = *(const bf16x8*)(Blbase + k0);
            bf16x8 bl1 = *(const bf16x8*)(Blbase + k0 + 16 * D_);
            acch[0][0] = __builtin_amdgcn_mfma_f32_16x16x32_bf16(a0, bh0, acch[0][0], 0, 0, 0);
            acch[0][1] = __builtin_amdgcn_mfma_f32_16x16x32_bf16(a0, bh1, acch[0][1], 0, 0, 0);
            acch[1][0] = __builtin_amdgcn_mfma_f32_16x16x32_bf16(a1, bh0, acch[1][0], 0, 0, 0);
            acch[1][1] = __builtin_amdgcn_mfma_f32_16x16x32_bf16(a1, bh1, acch[1][1], 0, 0, 0);
            accl[0][0] = __builtin_amdgcn_mfma_f32_16x16x32_bf16(a0, bl0, accl[0][0], 0, 0, 0);
            accl[0][1] = __builtin_amdgcn_mfma_f32_16x16x32_bf16(a0, bl1, accl[0][1], 0, 0, 0);
            accl[1][0] = __builtin_amdgcn_mfma_f32_16x16x32_bf16(a1, bl0, accl[1][0], 0, 0, 0);
            accl[1][1] = __builtin_amdgcn_mfma_f32_16x16x32_bf16(a1, bl1, accl[1][1], 0, 0, 0);
        }
        unsigned sb = 0;
        #pragma unroll
        for (int mi = 0; mi < 2; mi++)
            #pragma unroll
            for (int ni = 0; ni < 2; ni++)
                #pragma unroll
                for (int r = 0; r < 4; r++) {
                    int bit = mi * 8 + ni * 4 + r;
                    float y = acch[mi][ni][r] + accl[mi][ni][r];
                    float v = vstate[mi][ni][r] * 0.5f + y;
                    float d = v - 1.0f;
                    if (fabsf(d) < 1e-4f) flags |= (1u << bit);
                    float s = (d >= 0.f) ? 1.f : 0.f;
                    sb |= ((unsigned)(d >= 0.f)) << bit;
                    vstate[mi][ni][r] = v * (1.f - s);
                }
        sbits[t] = sb;
    }

    // fp64 refinement of near-threshold membrane trajectories (rare)
    if (flags) {
        for (int mi = 0; mi < 2; mi++)
            for (int ni = 0; ni < 2; ni++)
                for (int r = 0; r < 4; r++) {
                    int bit = mi * 8 + ni * 4 + r;
                    if (!(flags & (1u << bit))) continue;
                    int row = m0 + mi * 16 + quad * 4 + r;
                    int col = n0 + ni * 16 + m16;
                    const float* wr = Wf + (size_t)col * D_;
                    double v = 0.0;
                    for (int t = 0; t < T_; ++t) {
                        const bf16* ar = xs + ((size_t)(t * M2_ + row)) * D_;
                        double y = 0.0;
                        for (int k = 0; k < D_; ++k)
                            y += (double)(float)ar[k] * (double)wr[k];
                        v = v * 0.5 + y;
                        unsigned s = (v >= 1.0) ? 1u : 0u;
                        sbits[t] = (sbits[t] & ~(1u << bit)) | (s << bit);
                        if (s) v = 0.0;
                    }
                }
    }

    #pragma unroll
    for (int t = 0; t < T_; ++t)
        #pragma unroll
        for (int mi = 0; mi < 2; mi++)
            #pragma unroll
            for (int ni = 0; ni < 2; ni++)
                #pragma unroll
                for (int r = 0; r < 4; r++) {
                    int row = m0 + mi * 16 + quad * 4 + r;
                    int col = n0 + ni * 16 + m16;
                    float s = ((sbits[t] >> (mi * 8 + ni * 4 + r)) & 1) ? 1.f : 0.f;
                    out[((size_t)(t * M2_ + row)) * N + col] = (bf16)s;
                }
}

// ---------------------------------------------------------------------------
// Kernel 3: M_T[g][j][d] = sum_c k[c][d] * v[c][j]  (exact small integers)
// stored as exact hi/lo bf16 split. One block per g=(t*B+b)*HL+kvh.
// ---------------------------------------------------------------------------
__global__ __launch_bounds__(256) void ktv_kernel(
    const bf16* __restrict__ k_sp, const bf16* __restrict__ v_sp,
    bf16* __restrict__ M_hi, bf16* __restrict__ M_lo)
{
    const int g    = blockIdx.x;
    const int kvh  = g % HL_;
    const int tb   = g / HL_;
    const int wave = threadIdx.x >> 6;
    const int lane = threadIdx.x & 63;
    const int m16  = lane & 15, quad = lane >> 4;

    __shared__ __align__(16) bf16 klds[96 * 40];
    __shared__ __align__(16) bf16 vlds[96 * 40];

    f32x4 acc[9];
    #pragma unroll
    for (int i = 0; i < 9; i++) { f32x4 z = {0.f,0.f,0.f,0.f}; acc[i] = z; }

    const bf16* kbase = k_sp + ((size_t)tb * C_) * MKV_ + kvh * HD_;
    const bf16* vbase = v_sp + ((size_t)tb * C_) * MKV_ + kvh * HD_;

    for (int c0 = 0; c0 < C_; c0 += 32) {
        __syncthreads();
        for (int idx = threadIdx.x; idx < 32 * 96; idx += 256) {
            int d = idx % 96;
            int c = idx / 96;
            klds[d * 40 + c] = kbase[(size_t)(c0 + c) * MKV_ + d];
            vlds[d * 40 + c] = vbase[(size_t)(c0 + c) * MKV_ + d];
        }
        __syncthreads();
        #pragma unroll
        for (int i = 0; i < 9; i++) {
            int tile = wave + i * 4;          // 0..35 over 6m x 6n
            int mt = tile / 6, nt = tile % 6;
            bf16x8 a = *(const bf16x8*)(&klds[(mt * 16 + m16) * 40 + quad * 8]);
            bf16x8 b = *(const bf16x8*)(&vlds[(nt * 16 + m16) * 40 + quad * 8]);
            acc[i] = __builtin_amdgcn_mfma_f32_16x16x32_bf16(a, b, acc[i], 0, 0, 0);
        }
    }
    #pragma unroll
    for (int i = 0; i < 9; i++) {
        int tile = wave + i * 4;
        int mt = tile / 6, nt = tile % 6;
        #pragma unroll
        for (int r = 0; r < 4; r++) {
            int d = mt * 16 + quad * 4 + r;
            int j = nt * 16 + m16;
            float m = acc[i][r];
            bf16 h = (bf16)m;
            M_hi[((size_t)g * HD_ + j) * HD_ + d] = h;
            M_lo[((size_t)g * HD_ + j) * HD_ + d] = (bf16)(m - (float)h);
        }
    }
}

// ---------------------------------------------------------------------------
// Kernel 4: out_attn[tb,c,h*96+j] = 0.1 * sum_d q[tb,c,h*96+d] * M[g][d][j]
// Exact integer accumulation (hi+lo MFMA). Wave-tile 16c x 96j.
// ---------------------------------------------------------------------------
__global__ __launch_bounds__(256) void qm_kernel(
    const bf16* __restrict__ q_sp, const bf16* __restrict__ M_hi,
    const bf16* __restrict__ M_lo, bf16* __restrict__ out_attn)
{
    const int tbh  = blockIdx.x;
    const int h    = tbh % H_;
    const int tb   = tbh / H_;
    const int g    = tb * HL_ + (h >> 2);     // n_rep = 4
    const int wave = threadIdx.x >> 6;
    const int lane = threadIdx.x & 63;
    const int m16  = lane & 15, quad = lane >> 4;
    const int c0   = blockIdx.y * 64 + wave * 16;

    f32x4 acc[6];
    #pragma unroll
    for (int i = 0; i < 6; i++) { f32x4 z = {0.f,0.f,0.f,0.f}; acc[i] = z; }

    const bf16* Abase  = q_sp + ((size_t)(tb * C_ + c0 + m16)) * D_ + h * HD_;
    const bf16* Bhbase = M_hi + (size_t)g * HD_ * HD_ + m16 * HD_;
    const bf16* Blbase = M_lo + (size_t)g * HD_ * HD_ + m16 * HD_;
    #pragma unroll
    for (int ks = 0; ks < 3; ++ks) {
        bf16x8 a = *(const bf16x8*)(Abase + ks * 32 + quad * 8);
        #pragma unroll
        for (int nt = 0; nt < 6; ++nt) {
            bf16x8 bh = *(const bf16x8*)(Bhbase + nt * 16 * HD_ + ks * 32 + quad * 8);
            bf16x8 bl = *(const bf16x8*)(Blbase + nt * 16 * HD_ + ks * 32 + quad * 8);
            acc[nt] = __builtin_amdgcn_mfma_f32_16x16x32_bf16(a, bh, acc[nt], 0, 0, 0);
            acc[nt] = __builtin_amdgcn_mfma_f32_16x16x32_bf16(a, bl, acc[nt], 0, 0, 0);
        }
    }
    #pragma unroll
    for (int nt = 0; nt < 6; nt++)
        #pragma unroll
        for (int r = 0; r < 4; r++) {
            int c = c0 + quad * 4 + r;
            int j = nt * 16 + m16;
            out_attn[((size_t)(tb * C_ + c)) * D_ + h * HD_ + j] = (bf16)(0.1f * acc[nt][r]);
        }
}

// ---------------------------------------------------------------------------
// Kernel 5: final = out_attn @ wo^T  (plain bf16, fp32 output).
// ---------------------------------------------------------------------------
__global__ __launch_bounds__(256) void final_gemm_kernel(
    const bf16* __restrict__ A, const bf16* __restrict__ W,
    float* __restrict__ out)
{
    const int wave = threadIdx.x >> 6;
    const int lane = threadIdx.x & 63;
    const int m16  = lane & 15, quad = lane >> 4;
    const int ntiles = D_ / 32;               // 24
    const int gw = blockIdx.x * 4 + wave;
    const int n0 = (gw % ntiles) * 32;
    const int m0 = (gw / ntiles) * 32;

    f32x4 acc[2][2];
    #pragma unroll
    for (int a = 0; a < 2; a++)
        #pragma unroll
        for (int b = 0; b < 2; b++) { f32x4 z = {0.f,0.f,0.f,0.f}; acc[a][b] = z; }

    const bf16* Abase = A + ((size_t)(m0 + m16)) * D_ + quad * 8;
    const bf16* Bbase = W + ((size_t)(n0 + m16)) * D_ + quad * 8;
    for (int k0 = 0; k0 < D_; k0 += 32) {
        bf16x8 a0 = *(const bf16x8*)(Abase + k0);
        bf16x8 a1 = *(const bf16x8*)(Abase + k0 + 16 * D_);
        bf16x8 b0 = *(const bf16x8*)(Bbase + k0);
        bf16x8 b1 = *(const bf16x8*)(Bbase + k0 + 16 * D_);
        acc[0][0] = __builtin_amdgcn_mfma_f32_16x16x32_bf16(a0, b0, acc[0][0], 0, 0, 0);
        acc[0][1] = __builtin_amdgcn_mfma_f32_16x16x32_bf16(a0, b1, acc[0][1], 0, 0, 0);
        acc[1][0] = __builtin_amdgcn_mfma_f32_16x16x32_bf16(a1, b0, acc[1][0], 0, 0, 0);
        acc[1][1] = __builtin_amdgcn_mfma_f32_16x16x32_bf16(a1, b1, acc[1][1], 0, 0, 0);
    }
    #pragma unroll
    for (int mi = 0; mi < 2; mi++)
        #pragma unroll
        for (int ni = 0; ni < 2; ni++)
            #pragma unroll
            for (int r = 0; r < 4; r++) {
                int row = m0 + mi * 16 + quad * 4 + r;
                int col = n0 + ni * 16 + m16;
                out[(size_t)row * D_ + col] = acc[mi][ni][r];
            }
}

// ---------------------------------------------------------------------------
extern "C" void kernel_launch(void* const* d_in, const int* in_sizes, int n_in,
                              void* d_out, int out_size, void* d_ws, size_t ws_size,
                              hipStream_t stream) {
    const float* x    = (const float*)d_in[0];
    const float* q_w  = (const float*)d_in[1];
    const float* k_w  = (const float*)d_in[2];
    const float* v_w  = (const float*)d_in[3];
    const float* wo_w = (const float*)d_in[4];
    float* out = (float*)d_out;

    char* ws = (char*)d_ws;
    bf16* xs    = (bf16*)(ws);                  // 25,165,824  (T,M2,D)
    bf16* q_sp  = (bf16*)(ws + 25165824);       // 25,165,824  (T,M2,D)
    bf16* k_sp  = (bf16*)(ws + 50331648);       //  6,291,456  (T,M2,MKV)
    bf16* v_sp  = (bf16*)(ws + 56623104);       //  6,291,456  (T,M2,MKV)
    bf16* q_hi  = (bf16*)(ws + 62914560);       //  1,179,648
    bf16* q_lo  = (bf16*)(ws + 64094208);       //  1,179,648
    bf16* k_hi  = (bf16*)(ws + 65273856);       //    294,912
    bf16* k_lo  = (bf16*)(ws + 65568768);       //    294,912
    bf16* v_hi  = (bf16*)(ws + 65863680);       //    294,912
    bf16* v_lo  = (bf16*)(ws + 66158592);       //    294,912
    bf16* wo_bf = (bf16*)(ws + 66453504);       //  1,179,648
    bf16* M_hi  = (bf16*)(ws + 67633152);       //  1,179,648  (64,96,96)
    bf16* M_lo  = (bf16*)(ws + 68812800);       //  1,179,648
    bf16* out_attn = xs;                        // alias: xs dead after projections

    hipLaunchKernelGGL(lif_x_kernel, dim3(BCD_ / 256), dim3(256), 0, stream, x, xs);
    hipLaunchKernelGGL(split_w_kernel, dim3((D_ * D_) / 256), dim3(256), 0, stream,
                       q_w, q_hi, q_lo, D_ * D_);
    hipLaunchKernelGGL(split_w_kernel, dim3((MKV_ * D_) / 256), dim3(256), 0, stream,
                       k_w, k_hi, k_lo, MKV_ * D_);
    hipLaunchKernelGGL(split_w_kernel, dim3((MKV_ * D_) / 256), dim3(256), 0, stream,
                       v_w, v_hi, v_lo, MKV_ * D_);
    hipLaunchKernelGGL(cvt_w_kernel, dim3((D_ * D_) / 256), dim3(256), 0, stream,
                       wo_w, wo_bf, D_ * D_);

    hipLaunchKernelGGL(proj_lif_kernel, dim3(768), dim3(256), 0, stream,
                       xs, q_hi, q_lo, q_w, q_sp, D_);
    hipLaunchKernelGGL(proj_lif_kernel, dim3(192), dim3(256), 0, stream,
                       xs, k_hi, k_lo, k_w, k_sp, MKV_);
    hipLaunchKernelGGL(proj_lif_kernel, dim3(192), dim3(256), 0, stream,
                       xs, v_hi, v_lo, v_w, v_sp, MKV_);
    hipLaunchKernelGGL(ktv_kernel, dim3(T_ * B_ * HL_), dim3(256), 0, stream,
                       k_sp, v_sp, M_hi, M_lo);
    hipLaunchKernelGGL(qm_kernel, dim3(T_ * B_ * H_, C_ / 64), dim3(256), 0, stream,
                       q_sp, M_hi, M_lo, out_attn);
    hipLaunchKernelGGL(final_gemm_kernel, dim3((M3_ / 32) * (D_ / 32) / 4), dim3(256), 0, stream,
                       out_attn, wo_bf, out);
}

// Round 3
// 476.921 us; speedup vs baseline: 2.2698x; 2.2698x over previous
//
#include <hip/hip_runtime.h>

typedef __bf16 bf16;
typedef __bf16 bf16x8 __attribute__((ext_vector_type(8)));
typedef float f32x4 __attribute__((ext_vector_type(4)));

#define T_ 4
#define B_ 8
#define C_ 512
#define D_ 768
#define H_ 8
#define HL_ 2
#define HD_ 96
#define MKV_ 192
#define M2_ 4096            // B*C
#define BCD_ 3145728        // B*C*D
#define M3_ 16384           // T*B*C
#define NCOMB 1152          // q(768) + k(192) + v(192)
#define SUSP_CAP 65536
#define SUSP_WIN 2e-4f

// async global->LDS, 16B per lane (dest must be wave-uniform base + lane*16)
__device__ __forceinline__ void gld16(const bf16* g, bf16* l) {
    __builtin_amdgcn_global_load_lds(
        (const __attribute__((address_space(1))) unsigned int*)g,
        (__attribute__((address_space(3))) unsigned int*)l, 16, 0, 0);
}

// ---------------------------------------------------------------------------
// Kernel 1: xs = lif(x), fp64 scan (bit-matches numpy fp64 decisions).
// ---------------------------------------------------------------------------
__global__ __launch_bounds__(256) void lif_x_kernel(const float* __restrict__ x,
                                                    bf16* __restrict__ xs) {
    int i = blockIdx.x * blockDim.x + threadIdx.x;
    if (i >= BCD_) return;
    double v = 0.0;
    #pragma unroll
    for (int t = 0; t < T_; ++t) {
        v = v * 0.5 + (double)x[(size_t)t * BCD_ + i];
        float s = (v >= 1.0) ? 1.0f : 0.0f;
        xs[(size_t)t * BCD_ + i] = (bf16)s;
        if (s != 0.0f) v = 0.0;
    }
}

// ---------------------------------------------------------------------------
// Kernel 1b: split fp32 weight -> (hi, lo) bf16 pair (into combined buffer).
// ---------------------------------------------------------------------------
__global__ __launch_bounds__(256) void split_w_kernel(const float* __restrict__ w,
                                                      bf16* __restrict__ hi,
                                                      bf16* __restrict__ lo, int n) {
    int i = blockIdx.x * blockDim.x + threadIdx.x;
    if (i >= n) return;
    float v = w[i];
    bf16 h = (bf16)v;
    hi[i] = h;
    lo[i] = (bf16)(v - (float)h);
}

__global__ __launch_bounds__(256) void cvt_w_kernel(const float* __restrict__ w,
                                                    bf16* __restrict__ o, int n) {
    int i = blockIdx.x * blockDim.x + threadIdx.x;
    if (i >= n) return;
    o[i] = (bf16)w[i];
}

// ---------------------------------------------------------------------------
// Kernel 2: combined spiking projection. 128x128 block tile, LDS-staged
// (global_load_lds w=16), hi+lo MFMA into one fp32 acc, LIF fused over T.
// Near-threshold trajectories pushed to suspect list (fixed later).
//   xs: (T,M2,768) spikes ; Whi/Wlo: (1152,768) ; outputs split q/k/v.
// ---------------------------------------------------------------------------
__global__ __launch_bounds__(256) void proj_lif_kernel(
    const bf16* __restrict__ xs, const bf16* __restrict__ Whi,
    const bf16* __restrict__ Wlo,
    bf16* __restrict__ q_sp, bf16* __restrict__ k_sp, bf16* __restrict__ v_sp,
    unsigned* __restrict__ susp)
{
    __shared__ __align__(16) bf16 Alds[128 * 32];
    __shared__ __align__(16) bf16 Hlds[128 * 32];
    __shared__ __align__(16) bf16 Llds[128 * 32];

    const int tid  = threadIdx.x;
    const int wave = tid >> 6, lane = tid & 63;
    const int m16  = lane & 15, quad = lane >> 4;
    const int wm   = wave >> 1, wn = wave & 1;
    const int m0   = blockIdx.x * 128;
    const int n0   = blockIdx.y * 128;

    // staging chunk assignment: chunk ci -> (row ci/4, 8-elem seg ci%4)
    const int r0 = tid >> 2,        s0 = tid & 3;
    const int r1 = (tid + 256) >> 2, s1 = (tid + 256) & 3;

    // output section for this wave's 64 columns
    const int colb = n0 + wn * 64;
    bf16* outp; int Nloc, cb;
    if (colb < 768)      { outp = q_sp; Nloc = 768; cb = colb; }
    else if (colb < 960) { outp = k_sp; Nloc = 192; cb = colb - 768; }
    else                 { outp = v_sp; Nloc = 192; cb = colb - 960; }

    float vst[4][4][4];
    #pragma unroll
    for (int a = 0; a < 4; a++)
        #pragma unroll
        for (int b = 0; b < 4; b++)
            #pragma unroll
            for (int r = 0; r < 4; r++) vst[a][b][r] = 0.f;
    unsigned long long flags = 0;

    for (int t = 0; t < T_; ++t) {
        f32x4 acc[4][4];
        #pragma unroll
        for (int a = 0; a < 4; a++)
            #pragma unroll
            for (int b = 0; b < 4; b++) { f32x4 z = {0.f,0.f,0.f,0.f}; acc[a][b] = z; }

        const bf16* Ab = xs + (size_t)(t * M2_ + m0) * D_;
        for (int k0 = 0; k0 < D_; k0 += 32) {
            __syncthreads();
            gld16(Ab + (size_t)r0 * D_ + k0 + s0 * 8, Alds + tid * 8);
            gld16(Ab + (size_t)r1 * D_ + k0 + s1 * 8, Alds + (tid + 256) * 8);
            gld16(Whi + (size_t)(n0 + r0) * D_ + k0 + s0 * 8, Hlds + tid * 8);
            gld16(Whi + (size_t)(n0 + r1) * D_ + k0 + s1 * 8, Hlds + (tid + 256) * 8);
            gld16(Wlo + (size_t)(n0 + r0) * D_ + k0 + s0 * 8, Llds + tid * 8);
            gld16(Wlo + (size_t)(n0 + r1) * D_ + k0 + s1 * 8, Llds + (tid + 256) * 8);
            __syncthreads();

            bf16x8 a[4];
            #pragma unroll
            for (int mi = 0; mi < 4; mi++)
                a[mi] = *(const bf16x8*)&Alds[(wm * 64 + mi * 16 + m16) * 32 + quad * 8];
            #pragma unroll
            for (int ni = 0; ni < 4; ni++) {
                bf16x8 bh = *(const bf16x8*)&Hlds[(wn * 64 + ni * 16 + m16) * 32 + quad * 8];
                bf16x8 bl = *(const bf16x8*)&Llds[(wn * 64 + ni * 16 + m16) * 32 + quad * 8];
                #pragma unroll
                for (int mi = 0; mi < 4; mi++) {
                    acc[mi][ni] = __builtin_amdgcn_mfma_f32_16x16x32_bf16(a[mi], bh, acc[mi][ni], 0, 0, 0);
                    acc[mi][ni] = __builtin_amdgcn_mfma_f32_16x16x32_bf16(a[mi], bl, acc[mi][ni], 0, 0, 0);
                }
            }
        }

        // LIF epilogue + spike store for this t
        #pragma unroll
        for (int mi = 0; mi < 4; mi++)
            #pragma unroll
            for (int ni = 0; ni < 4; ni++)
                #pragma unroll
                for (int r = 0; r < 4; r++) {
                    float v = vst[mi][ni][r] * 0.5f + acc[mi][ni][r];
                    float d = v - 1.0f;
                    if (fabsf(d) < SUSP_WIN) flags |= (1ull << (mi * 16 + ni * 4 + r));
                    float s = (d >= 0.f) ? 1.f : 0.f;
                    vst[mi][ni][r] = v * (1.f - s);
                    int row = m0 + wm * 64 + mi * 16 + quad * 4 + r;
                    int lc  = cb + ni * 16 + m16;
                    outp[(size_t)(t * M2_ + row) * Nloc + lc] = (bf16)s;
                }
    }

    if (flags) {
        for (int mi = 0; mi < 4; mi++)
            for (int ni = 0; ni < 4; ni++)
                for (int r = 0; r < 4; r++)
                    if (flags & (1ull << (mi * 16 + ni * 4 + r))) {
                        int row  = m0 + wm * 64 + mi * 16 + quad * 4 + r;
                        int ccol = n0 + wn * 64 + ni * 16 + m16;
                        unsigned idx = atomicAdd(susp, 1u);
                        if (idx < SUSP_CAP) susp[1 + idx] = (unsigned)(row * 2048 + ccol);
                    }
    }
}

// ---------------------------------------------------------------------------
// Kernel 2b: fp64 fixup of suspect trajectories. One wave per suspect.
// ---------------------------------------------------------------------------
__global__ __launch_bounds__(256) void fixup_kernel(
    const bf16* __restrict__ xs, const float* __restrict__ q_w,
    const float* __restrict__ k_w, const float* __restrict__ v_w,
    bf16* __restrict__ q_sp, bf16* __restrict__ k_sp, bf16* __restrict__ v_sp,
    const unsigned* __restrict__ susp)
{
    unsigned count = susp[0];
    if (count > SUSP_CAP) count = SUSP_CAP;
    const int lane = threadIdx.x & 63;
    const int wid  = (blockIdx.x * blockDim.x + threadIdx.x) >> 6;
    const int nw   = (gridDim.x * blockDim.x) >> 6;
    for (unsigned i = wid; i < count; i += nw) {
        unsigned e = susp[1 + i];
        int row = e >> 11, col = e & 2047;
        const float* W; bf16* outp; int Nloc, lc;
        if (col < 768)      { W = q_w + (size_t)col * D_;        outp = q_sp; Nloc = 768; lc = col; }
        else if (col < 960) { W = k_w + (size_t)(col - 768) * D_; outp = k_sp; Nloc = 192; lc = col - 768; }
        else                { W = v_w + (size_t)(col - 960) * D_; outp = v_sp; Nloc = 192; lc = col - 960; }
        double v = 0.0;
        for (int t = 0; t < T_; ++t) {
            const bf16* ar = xs + (size_t)(t * M2_ + row) * D_;
            double y = 0.0;
            for (int k = lane; k < D_; k += 64)
                y += (double)(float)ar[k] * (double)W[k];
            #pragma unroll
            for (int off = 1; off < 64; off <<= 1)
                y += __shfl_xor(y, off);
            v = v * 0.5 + y;
            unsigned s = (v >= 1.0) ? 1u : 0u;
            if (lane == 0) outp[(size_t)(t * M2_ + row) * Nloc + lc] = (bf16)(float)s;
            if (s) v = 0.0;
        }
    }
}

// ---------------------------------------------------------------------------
// Kernel 3: M_T[g][j][d] = sum_c k[c][d]*v[c][j] (exact ints, hi/lo split).
// ---------------------------------------------------------------------------
__global__ __launch_bounds__(256) void ktv_kernel(
    const bf16* __restrict__ k_sp, const bf16* __restrict__ v_sp,
    bf16* __restrict__ M_hi, bf16* __restrict__ M_lo)
{
    const int g    = blockIdx.x;
    const int kvh  = g % HL_;
    const int tb   = g / HL_;
    const int wave = threadIdx.x >> 6;
    const int lane = threadIdx.x & 63;
    const int m16  = lane & 15, quad = lane >> 4;

    __shared__ __align__(16) bf16 klds[96 * 40];
    __shared__ __align__(16) bf16 vlds[96 * 40];

    f32x4 acc[9];
    #pragma unroll
    for (int i = 0; i < 9; i++) { f32x4 z = {0.f,0.f,0.f,0.f}; acc[i] = z; }

    const bf16* kbase = k_sp + ((size_t)tb * C_) * MKV_ + kvh * HD_;
    const bf16* vbase = v_sp + ((size_t)tb * C_) * MKV_ + kvh * HD_;

    for (int c0 = 0; c0 < C_; c0 += 32) {
        __syncthreads();
        for (int idx = threadIdx.x; idx < 32 * 96; idx += 256) {
            int d = idx % 96;
            int c = idx / 96;
            klds[d * 40 + c] = kbase[(size_t)(c0 + c) * MKV_ + d];
            vlds[d * 40 + c] = vbase[(size_t)(c0 + c) * MKV_ + d];
        }
        __syncthreads();
        #pragma unroll
        for (int i = 0; i < 9; i++) {
            int tile = wave + i * 4;
            int mt = tile / 6, nt = tile % 6;
            bf16x8 a = *(const bf16x8*)(&klds[(mt * 16 + m16) * 40 + quad * 8]);
            bf16x8 b = *(const bf16x8*)(&vlds[(nt * 16 + m16) * 40 + quad * 8]);
            acc[i] = __builtin_amdgcn_mfma_f32_16x16x32_bf16(a, b, acc[i], 0, 0, 0);
        }
    }
    #pragma unroll
    for (int i = 0; i < 9; i++) {
        int tile = wave + i * 4;
        int mt = tile / 6, nt = tile % 6;
        #pragma unroll
        for (int r = 0; r < 4; r++) {
            int d = mt * 16 + quad * 4 + r;
            int j = nt * 16 + m16;
            float m = acc[i][r];
            bf16 h = (bf16)m;
            M_hi[((size_t)g * HD_ + j) * HD_ + d] = h;
            M_lo[((size_t)g * HD_ + j) * HD_ + d] = (bf16)(m - (float)h);
        }
    }
}

// ---------------------------------------------------------------------------
// Kernel 4: out_attn = 0.1 * q @ M (exact int accumulation via hi/lo).
// ---------------------------------------------------------------------------
__global__ __launch_bounds__(256) void qm_kernel(
    const bf16* __restrict__ q_sp, const bf16* __restrict__ M_hi,
    const bf16* __restrict__ M_lo, bf16* __restrict__ out_attn)
{
    const int tbh  = blockIdx.x;
    const int h    = tbh % H_;
    const int tb   = tbh / H_;
    const int g    = tb * HL_ + (h >> 2);
    const int wave = threadIdx.x >> 6;
    const int lane = threadIdx.x & 63;
    const int m16  = lane & 15, quad = lane >> 4;
    const int c0   = blockIdx.y * 64 + wave * 16;

    f32x4 acc[6];
    #pragma unroll
    for (int i = 0; i < 6; i++) { f32x4 z = {0.f,0.f,0.f,0.f}; acc[i] = z; }

    const bf16* Abase  = q_sp + ((size_t)(tb * C_ + c0 + m16)) * D_ + h * HD_;
    const bf16* Bhbase = M_hi + (size_t)g * HD_ * HD_ + m16 * HD_;
    const bf16* Blbase = M_lo + (size_t)g * HD_ * HD_ + m16 * HD_;
    #pragma unroll
    for (int ks = 0; ks < 3; ++ks) {
        bf16x8 a = *(const bf16x8*)(Abase + ks * 32 + quad * 8);
        #pragma unroll
        for (int nt = 0; nt < 6; ++nt) {
            bf16x8 bh = *(const bf16x8*)(Bhbase + nt * 16 * HD_ + ks * 32 + quad * 8);
            bf16x8 bl = *(const bf16x8*)(Blbase + nt * 16 * HD_ + ks * 32 + quad * 8);
            acc[nt] = __builtin_amdgcn_mfma_f32_16x16x32_bf16(a, bh, acc[nt], 0, 0, 0);
            acc[nt] = __builtin_amdgcn_mfma_f32_16x16x32_bf16(a, bl, acc[nt], 0, 0, 0);
        }
    }
    #pragma unroll
    for (int nt = 0; nt < 6; nt++)
        #pragma unroll
        for (int r = 0; r < 4; r++) {
            int c = c0 + quad * 4 + r;
            int j = nt * 16 + m16;
            out_attn[((size_t)(tb * C_ + c)) * D_ + h * HD_ + j] = (bf16)(0.1f * acc[nt][r]);
        }
}

// ---------------------------------------------------------------------------
// Kernel 5: final = out_attn @ wo^T. 128x128 LDS-staged tile, fp32 out.
// ---------------------------------------------------------------------------
__global__ __launch_bounds__(256) void final_gemm_kernel(
    const bf16* __restrict__ A, const bf16* __restrict__ W, float* __restrict__ out)
{
    __shared__ __align__(16) bf16 Alds[128 * 32];
    __shared__ __align__(16) bf16 Blds[128 * 32];
    const int tid  = threadIdx.x;
    const int wave = tid >> 6, lane = tid & 63;
    const int m16  = lane & 15, quad = lane >> 4;
    const int wm   = wave >> 1, wn = wave & 1;
    const int m0   = blockIdx.x * 128, n0 = blockIdx.y * 128;
    const int r0 = tid >> 2,         s0 = tid & 3;
    const int r1 = (tid + 256) >> 2, s1 = (tid + 256) & 3;

    f32x4 acc[4][4];
    #pragma unroll
    for (int a = 0; a < 4; a++)
        #pragma unroll
        for (int b = 0; b < 4; b++) { f32x4 z = {0.f,0.f,0.f,0.f}; acc[a][b] = z; }

    for (int k0 = 0; k0 < D_; k0 += 32) {
        __syncthreads();
        gld16(A + (size_t)(m0 + r0) * D_ + k0 + s0 * 8, Alds + tid * 8);
        gld16(A + (size_t)(m0 + r1) * D_ + k0 + s1 * 8, Alds + (tid + 256) * 8);
        gld16(W + (size_t)(n0 + r0) * D_ + k0 + s0 * 8, Blds + tid * 8);
        gld16(W + (size_t)(n0 + r1) * D_ + k0 + s1 * 8, Blds + (tid + 256) * 8);
        __syncthreads();
        bf16x8 a[4], b[4];
        #pragma unroll
        for (int mi = 0; mi < 4; mi++)
            a[mi] = *(const bf16x8*)&Alds[(wm * 64 + mi * 16 + m16) * 32 + quad * 8];
        #pragma unroll
        for (int ni = 0; ni < 4; ni++)
            b[ni] = *(const bf16x8*)&Blds[(wn * 64 + ni * 16 + m16) * 32 + quad * 8];
        #pragma unroll
        for (int mi = 0; mi < 4; mi++)
            #pragma unroll
            for (int ni = 0; ni < 4; ni++)
                acc[mi][ni] = __builtin_amdgcn_mfma_f32_16x16x32_bf16(a[mi], b[ni], acc[mi][ni], 0, 0, 0);
    }
    #pragma unroll
    for (int mi = 0; mi < 4; mi++)
        #pragma unroll
        for (int ni = 0; ni < 4; ni++)
            #pragma unroll
            for (int r = 0; r < 4; r++) {
                int row = m0 + wm * 64 + mi * 16 + quad * 4 + r;
                int col = n0 + wn * 64 + ni * 16 + m16;
                out[(size_t)row * D_ + col] = acc[mi][ni][r];
            }
}

// ---------------------------------------------------------------------------
extern "C" void kernel_launch(void* const* d_in, const int* in_sizes, int n_in,
                              void* d_out, int out_size, void* d_ws, size_t ws_size,
                              hipStream_t stream) {
    const float* x    = (const float*)d_in[0];
    const float* q_w  = (const float*)d_in[1];
    const float* k_w  = (const float*)d_in[2];
    const float* v_w  = (const float*)d_in[3];
    const float* wo_w = (const float*)d_in[4];
    float* out = (float*)d_out;

    char* ws = (char*)d_ws;
    bf16* xs    = (bf16*)(ws);                  // 25,165,824  (T,M2,768)
    bf16* q_sp  = (bf16*)(ws + 25165824);       // 25,165,824  (T,M2,768)
    bf16* k_sp  = (bf16*)(ws + 50331648);       //  6,291,456  (T,M2,192)
    bf16* v_sp  = (bf16*)(ws + 56623104);       //  6,291,456  (T,M2,192)
    bf16* whi   = (bf16*)(ws + 62914560);       //  1,769,472  (1152,768)
    bf16* wlo   = (bf16*)(ws + 64684032);       //  1,769,472
    bf16* wo_bf = (bf16*)(ws + 66453504);       //  1,179,648
    bf16* M_hi  = (bf16*)(ws + 67633152);       //  1,179,648  (64,96,96)
    bf16* M_lo  = (bf16*)(ws + 68812800);       //  1,179,648
    unsigned* susp = (unsigned*)(ws + 69992448);//    262,148  (count + entries)
    bf16* out_attn = xs;                        // alias: xs dead after fixup+qm deps

    hipLaunchKernelGGL(lif_x_kernel, dim3(BCD_ / 256), dim3(256), 0, stream, x, xs);
    hipLaunchKernelGGL(split_w_kernel, dim3((D_ * D_) / 256), dim3(256), 0, stream,
                       q_w, whi, wlo, D_ * D_);
    hipLaunchKernelGGL(split_w_kernel, dim3((MKV_ * D_) / 256), dim3(256), 0, stream,
                       k_w, whi + (size_t)768 * D_, wlo + (size_t)768 * D_, MKV_ * D_);
    hipLaunchKernelGGL(split_w_kernel, dim3((MKV_ * D_) / 256), dim3(256), 0, stream,
                       v_w, whi + (size_t)960 * D_, wlo + (size_t)960 * D_, MKV_ * D_);
    hipLaunchKernelGGL(cvt_w_kernel, dim3((D_ * D_) / 256), dim3(256), 0, stream,
                       wo_w, wo_bf, D_ * D_);
    hipMemsetAsync(susp, 0, 4, stream);

    hipLaunchKernelGGL(proj_lif_kernel, dim3(M2_ / 128, NCOMB / 128), dim3(256), 0, stream,
                       xs, whi, wlo, q_sp, k_sp, v_sp, susp);
    hipLaunchKernelGGL(fixup_kernel, dim3(256), dim3(256), 0, stream,
                       xs, q_w, k_w, v_w, q_sp, k_sp, v_sp, susp);
    hipLaunchKernelGGL(ktv_kernel, dim3(T_ * B_ * HL_), dim3(256), 0, stream,
                       k_sp, v_sp, M_hi, M_lo);
    hipLaunchKernelGGL(qm_kernel, dim3(T_ * B_ * H_, C_ / 64), dim3(256), 0, stream,
                       q_sp, M_hi, M_lo, out_attn);
    hipLaunchKernelGGL(final_gemm_kernel, dim3(M3_ / 128, D_ / 128), dim3(256), 0, stream,
                       out_attn, wo_bf, out);
}

// Round 4
// 366.533 us; speedup vs baseline: 2.9534x; 1.3012x over previous
//
#include <hip/hip_runtime.h>

typedef __bf16 bf16;
typedef __bf16 bf16x8 __attribute__((ext_vector_type(8)));
typedef float f32x4 __attribute__((ext_vector_type(4)));

#define T_ 4
#define B_ 8
#define C_ 512
#define D_ 768
#define H_ 8
#define HL_ 2
#define HD_ 96
#define MKV_ 192
#define M2_ 4096            // B*C
#define BCD_ 3145728        // B*C*D
#define M3_ 16384           // T*B*C
#define NCOMB 1152          // q(768) + k(192) + v(192)
#define SUSP_CAP 65536
#define SUSP_WIN 2e-4f

// async global->LDS, 16B per lane (dest must be wave-uniform base + lane*16)
__device__ __forceinline__ void gld16(const bf16* g, bf16* l) {
    __builtin_amdgcn_global_load_lds(
        (const __attribute__((address_space(1))) unsigned int*)g,
        (__attribute__((address_space(3))) unsigned int*)l, 16, 0, 0);
}

// ---------------------------------------------------------------------------
// Kernel 1: xs = lif(x), fp64 scan (bit-matches numpy fp64 decisions).
// ---------------------------------------------------------------------------
__global__ __launch_bounds__(256) void lif_x_kernel(const float* __restrict__ x,
                                                    bf16* __restrict__ xs) {
    int i = blockIdx.x * blockDim.x + threadIdx.x;
    if (i >= BCD_) return;
    double v = 0.0;
    #pragma unroll
    for (int t = 0; t < T_; ++t) {
        v = v * 0.5 + (double)x[(size_t)t * BCD_ + i];
        float s = (v >= 1.0) ? 1.0f : 0.0f;
        xs[(size_t)t * BCD_ + i] = (bf16)s;
        if (s != 0.0f) v = 0.0;
    }
}

// ---------------------------------------------------------------------------
// Kernel 1b: split all three fp32 projection weights -> combined (hi,lo)
// bf16 buffers, rows [0,768)=q, [768,960)=k, [960,1152)=v.
// ---------------------------------------------------------------------------
__global__ __launch_bounds__(256) void split_all_kernel(
    const float* __restrict__ q_w, const float* __restrict__ k_w,
    const float* __restrict__ v_w, bf16* __restrict__ hi, bf16* __restrict__ lo)
{
    int i = blockIdx.x * blockDim.x + threadIdx.x;
    if (i >= NCOMB * D_) return;
    int row = i / D_, col = i - row * D_;
    float v;
    if (row < 768)      v = q_w[(size_t)row * D_ + col];
    else if (row < 960) v = k_w[(size_t)(row - 768) * D_ + col];
    else                v = v_w[(size_t)(row - 960) * D_ + col];
    bf16 h = (bf16)v;
    hi[i] = h;
    lo[i] = (bf16)(v - (float)h);
}

__global__ __launch_bounds__(256) void cvt_w_kernel(const float* __restrict__ w,
                                                    bf16* __restrict__ o, int n) {
    int i = blockIdx.x * blockDim.x + threadIdx.x;
    if (i >= n) return;
    o[i] = (bf16)w[i];
}

// ---------------------------------------------------------------------------
// Kernel 2: combined spiking projection, T-fused-in-registers.
// Block tile 64(m2) x 64(n); each wave 32x32 with acc[t=4][2][2].
// K-loop stages A for all 4 t (shared B), 24 steps. LIF scan in epilogue.
// Near-threshold trajectories pushed to suspect list (fp64 fixup later).
// ---------------------------------------------------------------------------
__global__ __launch_bounds__(256) void proj_lif_kernel(
    const bf16* __restrict__ xs, const bf16* __restrict__ Whi,
    const bf16* __restrict__ Wlo,
    bf16* __restrict__ q_sp, bf16* __restrict__ k_sp, bf16* __restrict__ v_sp,
    unsigned* __restrict__ susp)
{
    __shared__ __align__(16) bf16 Alds[T_][64 * 32];
    __shared__ __align__(16) bf16 Hlds[64 * 32];
    __shared__ __align__(16) bf16 Llds[64 * 32];

    const int tid  = threadIdx.x;
    const int wave = tid >> 6, lane = tid & 63;
    const int m16  = lane & 15, quad = lane >> 4;
    const int wm   = wave >> 1, wn = wave & 1;
    const int m0   = blockIdx.x * 64;          // over M2 (4096)
    const int n0   = blockIdx.y * 64;          // over NCOMB (1152)
    const int r    = tid >> 2, s = tid & 3;    // staging: row, 8-elem segment

    // output section for this wave's 32 columns (64-col blocks never straddle)
    const int colb = n0 + wn * 32;
    bf16* outp; int Nloc, cb;
    if (colb < 768)      { outp = q_sp; Nloc = 768; cb = colb; }
    else if (colb < 960) { outp = k_sp; Nloc = 192; cb = colb - 768; }
    else                 { outp = v_sp; Nloc = 192; cb = colb - 960; }

    f32x4 acc[T_][2][2];
    #pragma unroll
    for (int t = 0; t < T_; t++)
        #pragma unroll
        for (int a = 0; a < 2; a++)
            #pragma unroll
            for (int b = 0; b < 2; b++) { f32x4 z = {0.f,0.f,0.f,0.f}; acc[t][a][b] = z; }

    for (int k0 = 0; k0 < D_; k0 += 32) {
        __syncthreads();
        #pragma unroll
        for (int t = 0; t < T_; t++)
            gld16(xs + (size_t)(t * M2_ + m0 + r) * D_ + k0 + s * 8, &Alds[t][tid * 8]);
        gld16(Whi + (size_t)(n0 + r) * D_ + k0 + s * 8, Hlds + tid * 8);
        gld16(Wlo + (size_t)(n0 + r) * D_ + k0 + s * 8, Llds + tid * 8);
        __syncthreads();

        bf16x8 a[T_][2];
        #pragma unroll
        for (int t = 0; t < T_; t++)
            #pragma unroll
            for (int mi = 0; mi < 2; mi++)
                a[t][mi] = *(const bf16x8*)&Alds[t][(wm * 32 + mi * 16 + m16) * 32 + quad * 8];
        #pragma unroll
        for (int ni = 0; ni < 2; ni++) {
            bf16x8 bh = *(const bf16x8*)&Hlds[(wn * 32 + ni * 16 + m16) * 32 + quad * 8];
            bf16x8 bl = *(const bf16x8*)&Llds[(wn * 32 + ni * 16 + m16) * 32 + quad * 8];
            #pragma unroll
            for (int t = 0; t < T_; t++)
                #pragma unroll
                for (int mi = 0; mi < 2; mi++) {
                    acc[t][mi][ni] = __builtin_amdgcn_mfma_f32_16x16x32_bf16(a[t][mi], bh, acc[t][mi][ni], 0, 0, 0);
                    acc[t][mi][ni] = __builtin_amdgcn_mfma_f32_16x16x32_bf16(a[t][mi], bl, acc[t][mi][ni], 0, 0, 0);
                }
        }
    }

    // LIF scan over t (registers only) + spike stores + suspect flags
    #pragma unroll
    for (int mi = 0; mi < 2; mi++)
        #pragma unroll
        for (int ni = 0; ni < 2; ni++)
            #pragma unroll
            for (int rr = 0; rr < 4; rr++) {
                int row = m0 + wm * 32 + mi * 16 + quad * 4 + rr;
                int lc  = cb + ni * 16 + m16;
                float v = 0.f;
                bool suspect = false;
                #pragma unroll
                for (int t = 0; t < T_; t++) {
                    v = v * 0.5f + acc[t][mi][ni][rr];
                    float d = v - 1.0f;
                    if (fabsf(d) < SUSP_WIN) suspect = true;
                    float sp = (d >= 0.f) ? 1.f : 0.f;
                    v *= (1.f - sp);
                    outp[(size_t)(t * M2_ + row) * Nloc + lc] = (bf16)sp;
                }
                if (suspect) {
                    int ccol = n0 + wn * 32 + ni * 16 + m16;
                    unsigned idx = atomicAdd(susp, 1u);
                    if (idx < SUSP_CAP) susp[1 + idx] = (unsigned)(row * 2048 + ccol);
                }
            }
}

// ---------------------------------------------------------------------------
// Kernel 2b: fp64 fixup of suspect trajectories. One wave per suspect.
// ---------------------------------------------------------------------------
__global__ __launch_bounds__(256) void fixup_kernel(
    const bf16* __restrict__ xs, const float* __restrict__ q_w,
    const float* __restrict__ k_w, const float* __restrict__ v_w,
    bf16* __restrict__ q_sp, bf16* __restrict__ k_sp, bf16* __restrict__ v_sp,
    const unsigned* __restrict__ susp)
{
    unsigned count = susp[0];
    if (count > SUSP_CAP) count = SUSP_CAP;
    const int lane = threadIdx.x & 63;
    const int wid  = (blockIdx.x * blockDim.x + threadIdx.x) >> 6;
    const int nw   = (gridDim.x * blockDim.x) >> 6;
    for (unsigned i = wid; i < count; i += nw) {
        unsigned e = susp[1 + i];
        int row = e >> 11, col = e & 2047;
        const float* W; bf16* outp; int Nloc, lc;
        if (col < 768)      { W = q_w + (size_t)col * D_;         outp = q_sp; Nloc = 768; lc = col; }
        else if (col < 960) { W = k_w + (size_t)(col - 768) * D_; outp = k_sp; Nloc = 192; lc = col - 768; }
        else                { W = v_w + (size_t)(col - 960) * D_; outp = v_sp; Nloc = 192; lc = col - 960; }
        double v = 0.0;
        for (int t = 0; t < T_; ++t) {
            const bf16* ar = xs + (size_t)(t * M2_ + row) * D_;
            double y = 0.0;
            for (int k = lane; k < D_; k += 64)
                y += (double)(float)ar[k] * (double)W[k];
            #pragma unroll
            for (int off = 1; off < 64; off <<= 1)
                y += __shfl_xor(y, off);
            v = v * 0.5 + y;
            unsigned sp = (v >= 1.0) ? 1u : 0u;
            if (lane == 0) outp[(size_t)(t * M2_ + row) * Nloc + lc] = (bf16)(float)sp;
            if (sp) v = 0.0;
        }
    }
}

// ---------------------------------------------------------------------------
// Kernel 3: M_T[g][j][d] = sum_c k[c][d]*v[c][j] (exact ints, hi/lo split).
// ---------------------------------------------------------------------------
__global__ __launch_bounds__(256) void ktv_kernel(
    const bf16* __restrict__ k_sp, const bf16* __restrict__ v_sp,
    bf16* __restrict__ M_hi, bf16* __restrict__ M_lo)
{
    const int g    = blockIdx.x;
    const int kvh  = g % HL_;
    const int tb   = g / HL_;
    const int wave = threadIdx.x >> 6;
    const int lane = threadIdx.x & 63;
    const int m16  = lane & 15, quad = lane >> 4;

    __shared__ __align__(16) bf16 klds[96 * 40];
    __shared__ __align__(16) bf16 vlds[96 * 40];

    f32x4 acc[9];
    #pragma unroll
    for (int i = 0; i < 9; i++) { f32x4 z = {0.f,0.f,0.f,0.f}; acc[i] = z; }

    const bf16* kbase = k_sp + ((size_t)tb * C_) * MKV_ + kvh * HD_;
    const bf16* vbase = v_sp + ((size_t)tb * C_) * MKV_ + kvh * HD_;

    for (int c0 = 0; c0 < C_; c0 += 32) {
        __syncthreads();
        for (int idx = threadIdx.x; idx < 32 * 96; idx += 256) {
            int d = idx % 96;
            int c = idx / 96;
            klds[d * 40 + c] = kbase[(size_t)(c0 + c) * MKV_ + d];
            vlds[d * 40 + c] = vbase[(size_t)(c0 + c) * MKV_ + d];
        }
        __syncthreads();
        #pragma unroll
        for (int i = 0; i < 9; i++) {
            int tile = wave + i * 4;
            int mt = tile / 6, nt = tile % 6;
            bf16x8 a = *(const bf16x8*)(&klds[(mt * 16 + m16) * 40 + quad * 8]);
            bf16x8 b = *(const bf16x8*)(&vlds[(nt * 16 + m16) * 40 + quad * 8]);
            acc[i] = __builtin_amdgcn_mfma_f32_16x16x32_bf16(a, b, acc[i], 0, 0, 0);
        }
    }
    #pragma unroll
    for (int i = 0; i < 9; i++) {
        int tile = wave + i * 4;
        int mt = tile / 6, nt = tile % 6;
        #pragma unroll
        for (int r = 0; r < 4; r++) {
            int d = mt * 16 + quad * 4 + r;
            int j = nt * 16 + m16;
            float m = acc[i][r];
            bf16 h = (bf16)m;
            M_hi[((size_t)g * HD_ + j) * HD_ + d] = h;
            M_lo[((size_t)g * HD_ + j) * HD_ + d] = (bf16)(m - (float)h);
        }
    }
}

// ---------------------------------------------------------------------------
// Kernel 4: out_attn = 0.1 * q @ M (exact int accumulation via hi/lo).
// ---------------------------------------------------------------------------
__global__ __launch_bounds__(256) void qm_kernel(
    const bf16* __restrict__ q_sp, const bf16* __restrict__ M_hi,
    const bf16* __restrict__ M_lo, bf16* __restrict__ out_attn)
{
    const int tbh  = blockIdx.x;
    const int h    = tbh % H_;
    const int tb   = tbh / H_;
    const int g    = tb * HL_ + (h >> 2);
    const int wave = threadIdx.x >> 6;
    const int lane = threadIdx.x & 63;
    const int m16  = lane & 15, quad = lane >> 4;
    const int c0   = blockIdx.y * 64 + wave * 16;

    f32x4 acc[6];
    #pragma unroll
    for (int i = 0; i < 6; i++) { f32x4 z = {0.f,0.f,0.f,0.f}; acc[i] = z; }

    const bf16* Abase  = q_sp + ((size_t)(tb * C_ + c0 + m16)) * D_ + h * HD_;
    const bf16* Bhbase = M_hi + (size_t)g * HD_ * HD_ + m16 * HD_;
    const bf16* Blbase = M_lo + (size_t)g * HD_ * HD_ + m16 * HD_;
    #pragma unroll
    for (int ks = 0; ks < 3; ++ks) {
        bf16x8 a = *(const bf16x8*)(Abase + ks * 32 + quad * 8);
        #pragma unroll
        for (int nt = 0; nt < 6; ++nt) {
            bf16x8 bh = *(const bf16x8*)(Bhbase + nt * 16 * HD_ + ks * 32 + quad * 8);
            bf16x8 bl = *(const bf16x8*)(Blbase + nt * 16 * HD_ + ks * 32 + quad * 8);
            acc[nt] = __builtin_amdgcn_mfma_f32_16x16x32_bf16(a, bh, acc[nt], 0, 0, 0);
            acc[nt] = __builtin_amdgcn_mfma_f32_16x16x32_bf16(a, bl, acc[nt], 0, 0, 0);
        }
    }
    #pragma unroll
    for (int nt = 0; nt < 6; nt++)
        #pragma unroll
        for (int r = 0; r < 4; r++) {
            int c = c0 + quad * 4 + r;
            int j = nt * 16 + m16;
            out_attn[((size_t)(tb * C_ + c)) * D_ + h * HD_ + j] = (bf16)(0.1f * acc[nt][r]);
        }
}

// ---------------------------------------------------------------------------
// Kernel 5: final = out_attn @ wo^T. 128x128 LDS-staged tile, fp32 out.
// ---------------------------------------------------------------------------
__global__ __launch_bounds__(256) void final_gemm_kernel(
    const bf16* __restrict__ A, const bf16* __restrict__ W, float* __restrict__ out)
{
    __shared__ __align__(16) bf16 Alds[128 * 32];
    __shared__ __align__(16) bf16 Blds[128 * 32];
    const int tid  = threadIdx.x;
    const int wave = tid >> 6, lane = tid & 63;
    const int m16  = lane & 15, quad = lane >> 4;
    const int wm   = wave >> 1, wn = wave & 1;
    const int m0   = blockIdx.x * 128, n0 = blockIdx.y * 128;
    const int r0 = tid >> 2,         s0 = tid & 3;
    const int r1 = (tid + 256) >> 2, s1 = (tid + 256) & 3;

    f32x4 acc[4][4];
    #pragma unroll
    for (int a = 0; a < 4; a++)
        #pragma unroll
        for (int b = 0; b < 4; b++) { f32x4 z = {0.f,0.f,0.f,0.f}; acc[a][b] = z; }

    for (int k0 = 0; k0 < D_; k0 += 32) {
        __syncthreads();
        gld16(A + (size_t)(m0 + r0) * D_ + k0 + s0 * 8, Alds + tid * 8);
        gld16(A + (size_t)(m0 + r1) * D_ + k0 + s1 * 8, Alds + (tid + 256) * 8);
        gld16(W + (size_t)(n0 + r0) * D_ + k0 + s0 * 8, Blds + tid * 8);
        gld16(W + (size_t)(n0 + r1) * D_ + k0 + s1 * 8, Blds + (tid + 256) * 8);
        __syncthreads();
        bf16x8 a[4], b[4];
        #pragma unroll
        for (int mi = 0; mi < 4; mi++)
            a[mi] = *(const bf16x8*)&Alds[(wm * 64 + mi * 16 + m16) * 32 + quad * 8];
        #pragma unroll
        for (int ni = 0; ni < 4; ni++)
            b[ni] = *(const bf16x8*)&Blds[(wn * 64 + ni * 16 + m16) * 32 + quad * 8];
        #pragma unroll
        for (int mi = 0; mi < 4; mi++)
            #pragma unroll
            for (int ni = 0; ni < 4; ni++)
                acc[mi][ni] = __builtin_amdgcn_mfma_f32_16x16x32_bf16(a[mi], b[ni], acc[mi][ni], 0, 0, 0);
    }
    #pragma unroll
    for (int mi = 0; mi < 4; mi++)
        #pragma unroll
        for (int ni = 0; ni < 4; ni++)
            #pragma unroll
            for (int r = 0; r < 4; r++) {
                int row = m0 + wm * 64 + mi * 16 + quad * 4 + r;
                int col = n0 + wn * 64 + ni * 16 + m16;
                out[(size_t)row * D_ + col] = acc[mi][ni][r];
            }
}

// ---------------------------------------------------------------------------
extern "C" void kernel_launch(void* const* d_in, const int* in_sizes, int n_in,
                              void* d_out, int out_size, void* d_ws, size_t ws_size,
                              hipStream_t stream) {
    const float* x    = (const float*)d_in[0];
    const float* q_w  = (const float*)d_in[1];
    const float* k_w  = (const float*)d_in[2];
    const float* v_w  = (const float*)d_in[3];
    const float* wo_w = (const float*)d_in[4];
    float* out = (float*)d_out;

    char* ws = (char*)d_ws;
    bf16* xs    = (bf16*)(ws);                  // 25,165,824  (T,M2,768)
    bf16* q_sp  = (bf16*)(ws + 25165824);       // 25,165,824  (T,M2,768)
    bf16* k_sp  = (bf16*)(ws + 50331648);       //  6,291,456  (T,M2,192)
    bf16* v_sp  = (bf16*)(ws + 56623104);       //  6,291,456  (T,M2,192)
    bf16* whi   = (bf16*)(ws + 62914560);       //  1,769,472  (1152,768)
    bf16* wlo   = (bf16*)(ws + 64684032);       //  1,769,472
    bf16* wo_bf = (bf16*)(ws + 66453504);       //  1,179,648
    bf16* M_hi  = (bf16*)(ws + 67633152);       //  1,179,648  (64,96,96)
    bf16* M_lo  = (bf16*)(ws + 68812800);       //  1,179,648
    unsigned* susp = (unsigned*)(ws + 69992448);//    262,148  (count + entries)
    bf16* out_attn = xs;                        // alias: xs dead after fixup+qm deps

    hipLaunchKernelGGL(lif_x_kernel, dim3(BCD_ / 256), dim3(256), 0, stream, x, xs);
    hipLaunchKernelGGL(split_all_kernel, dim3((NCOMB * D_) / 256), dim3(256), 0, stream,
                       q_w, k_w, v_w, whi, wlo);
    hipLaunchKernelGGL(cvt_w_kernel, dim3((D_ * D_) / 256), dim3(256), 0, stream,
                       wo_w, wo_bf, D_ * D_);
    hipMemsetAsync(susp, 0, 4, stream);

    hipLaunchKernelGGL(proj_lif_kernel, dim3(M2_ / 64, NCOMB / 64), dim3(256), 0, stream,
                       xs, whi, wlo, q_sp, k_sp, v_sp, susp);
    hipLaunchKernelGGL(fixup_kernel, dim3(256), dim3(256), 0, stream,
                       xs, q_w, k_w, v_w, q_sp, k_sp, v_sp, susp);
    hipLaunchKernelGGL(ktv_kernel, dim3(T_ * B_ * HL_), dim3(256), 0, stream,
                       k_sp, v_sp, M_hi, M_lo);
    hipLaunchKernelGGL(qm_kernel, dim3(T_ * B_ * H_, C_ / 64), dim3(256), 0, stream,
                       q_sp, M_hi, M_lo, out_attn);
    hipLaunchKernelGGL(final_gemm_kernel, dim3(M3_ / 128, D_ / 128), dim3(256), 0, stream,
                       out_attn, wo_bf, out);
}

// Round 5
// 279.591 us; speedup vs baseline: 3.8717x; 1.3110x over previous
//
#include <hip/hip_runtime.h>

typedef __bf16 bf16;
typedef __bf16 bf16x8 __attribute__((ext_vector_type(8)));
typedef float f32x4 __attribute__((ext_vector_type(4)));

#define T_ 4
#define B_ 8
#define C_ 512
#define D_ 768
#define H_ 8
#define HL_ 2
#define HD_ 96
#define MKV_ 192
#define M2_ 4096            // B*C
#define BCD_ 3145728        // B*C*D
#define M3_ 16384           // T*B*C
#define NCOMB 1152          // q(768) + k(192) + v(192)
#define SUSP_CAP 65536
#define SUSP_WIN 2e-4f

// async global->LDS, 16B per lane (dest = wave-uniform base + lane*16; no pad)
__device__ __forceinline__ void gld16(const bf16* g, bf16* l) {
    __builtin_amdgcn_global_load_lds(
        (const __attribute__((address_space(1))) unsigned int*)g,
        (__attribute__((address_space(3))) unsigned int*)l, 16, 0, 0);
}

// ---------------------------------------------------------------------------
// Kernel 1: fused prep — xs=lif(x) fp64 scan, q/k/v weight hi/lo split,
// wo bf16 cvt, susp counter reset. Grid-stride.
// ---------------------------------------------------------------------------
__global__ __launch_bounds__(256) void prep_kernel(
    const float* __restrict__ x, const float* __restrict__ q_w,
    const float* __restrict__ k_w, const float* __restrict__ v_w,
    const float* __restrict__ wo_w, bf16* __restrict__ xs,
    bf16* __restrict__ whi, bf16* __restrict__ wlo, bf16* __restrict__ wo_bf,
    unsigned* __restrict__ susp)
{
    const int t0 = blockIdx.x * 256 + threadIdx.x;
    const int stride = gridDim.x * 256;
    if (t0 == 0) susp[0] = 0;
    for (int i = t0; i < BCD_; i += stride) {
        double v = 0.0;
        #pragma unroll
        for (int t = 0; t < T_; ++t) {
            v = v * 0.5 + (double)x[(size_t)t * BCD_ + i];
            float s = (v >= 1.0) ? 1.0f : 0.0f;
            xs[(size_t)t * BCD_ + i] = (bf16)s;
            if (s != 0.0f) v = 0.0;
        }
    }
    for (int i = t0; i < NCOMB * D_; i += stride) {
        int row = i / D_, col = i - row * D_;
        float v;
        if (row < 768)      v = q_w[(size_t)row * D_ + col];
        else if (row < 960) v = k_w[(size_t)(row - 768) * D_ + col];
        else                v = v_w[(size_t)(row - 960) * D_ + col];
        bf16 h = (bf16)v;
        whi[i] = h;
        wlo[i] = (bf16)(v - (float)h);
    }
    for (int i = t0; i < D_ * D_; i += stride)
        wo_bf[i] = (bf16)wo_w[i];
}

// ---------------------------------------------------------------------------
// Kernel 2: combined spiking projection. Block 64(m)x64(n), BK=64,
// T fused in registers (acc[4][2][2]). XOR-swizzled LDS (conflict-free
// b128 reads, gld16-compatible). LIF scan in epilogue; suspects -> list.
// ---------------------------------------------------------------------------
__global__ __launch_bounds__(256) void proj_lif_kernel(
    const bf16* __restrict__ xs, const bf16* __restrict__ Whi,
    const bf16* __restrict__ Wlo,
    bf16* __restrict__ q_sp, bf16* __restrict__ k_sp, bf16* __restrict__ v_sp,
    unsigned* __restrict__ susp)
{
    __shared__ __align__(16) bf16 Alds[T_][64 * 64];   // 32 KB
    __shared__ __align__(16) bf16 Hlds[64 * 64];       // 8 KB
    __shared__ __align__(16) bf16 Llds[64 * 64];       // 8 KB

    const int tid  = threadIdx.x;
    const int wave = tid >> 6, lane = tid & 63;
    const int m16  = lane & 15, quad = lane >> 4;
    const int wm   = wave >> 1, wn = wave & 1;
    const int m0   = blockIdx.x * 64;          // over M2
    const int n0   = blockIdx.y * 64;          // over NCOMB

    // output section for this wave's 32 columns
    const int colb = n0 + wn * 32;
    bf16* outp; int Nloc, cb;
    if (colb < 768)      { outp = q_sp; Nloc = 768; cb = colb; }
    else if (colb < 960) { outp = k_sp; Nloc = 192; cb = colb - 768; }
    else                 { outp = v_sp; Nloc = 192; cb = colb - 960; }

    f32x4 acc[T_][2][2];
    #pragma unroll
    for (int t = 0; t < T_; t++)
        #pragma unroll
        for (int a = 0; a < 2; a++)
            #pragma unroll
            for (int b = 0; b < 2; b++) { f32x4 z = {0.f,0.f,0.f,0.f}; acc[t][a][b] = z; }

    for (int k0 = 0; k0 < D_; k0 += 64) {
        __syncthreads();
        // stage A: 4t x 64rows x 8slots = 2048 chunks; slot s holds seg s^f(row)
        #pragma unroll
        for (int j = 0; j < 8; j++) {
            int ci = j * 256 + tid;
            int t = ci >> 9, rem = ci & 511, row = rem >> 3, slot = rem & 7;
            int seg = slot ^ ((row >> 1) & 7);
            gld16(xs + (size_t)(t * M2_ + m0 + row) * D_ + k0 + seg * 8, &Alds[t][rem * 8]);
        }
        // stage B hi/lo: 64rows x 8slots = 512 chunks each
        #pragma unroll
        for (int j = 0; j < 2; j++) {
            int ci = j * 256 + tid;
            int row = ci >> 3, slot = ci & 7;
            int seg = slot ^ ((row >> 1) & 7);
            gld16(Whi + (size_t)(n0 + row) * D_ + k0 + seg * 8, Hlds + ci * 8);
            gld16(Wlo + (size_t)(n0 + row) * D_ + k0 + seg * 8, Llds + ci * 8);
        }
        __syncthreads();

        #pragma unroll
        for (int kc = 0; kc < 2; kc++) {
            bf16x8 a[T_][2], bh[2], bl[2];
            #pragma unroll
            for (int mi = 0; mi < 2; mi++) {
                int row = wm * 32 + mi * 16 + m16;
                int off = row * 64 + (((kc * 4 + quad) ^ ((row >> 1) & 7)) * 8);
                #pragma unroll
                for (int t = 0; t < T_; t++)
                    a[t][mi] = *(const bf16x8*)&Alds[t][off];
            }
            #pragma unroll
            for (int ni = 0; ni < 2; ni++) {
                int row = wn * 32 + ni * 16 + m16;
                int off = row * 64 + (((kc * 4 + quad) ^ ((row >> 1) & 7)) * 8);
                bh[ni] = *(const bf16x8*)&Hlds[off];
                bl[ni] = *(const bf16x8*)&Llds[off];
            }
            #pragma unroll
            for (int ni = 0; ni < 2; ni++)
                #pragma unroll
                for (int t = 0; t < T_; t++)
                    #pragma unroll
                    for (int mi = 0; mi < 2; mi++) {
                        acc[t][mi][ni] = __builtin_amdgcn_mfma_f32_16x16x32_bf16(a[t][mi], bh[ni], acc[t][mi][ni], 0, 0, 0);
                        acc[t][mi][ni] = __builtin_amdgcn_mfma_f32_16x16x32_bf16(a[t][mi], bl[ni], acc[t][mi][ni], 0, 0, 0);
                    }
        }
    }

    // LIF scan over t (registers only) + spike stores + suspect flags
    #pragma unroll
    for (int mi = 0; mi < 2; mi++)
        #pragma unroll
        for (int ni = 0; ni < 2; ni++)
            #pragma unroll
            for (int rr = 0; rr < 4; rr++) {
                int row = m0 + wm * 32 + mi * 16 + quad * 4 + rr;
                int lc  = cb + ni * 16 + m16;
                float v = 0.f;
                bool suspect = false;
                #pragma unroll
                for (int t = 0; t < T_; t++) {
                    v = v * 0.5f + acc[t][mi][ni][rr];
                    float d = v - 1.0f;
                    if (fabsf(d) < SUSP_WIN) suspect = true;
                    float sp = (d >= 0.f) ? 1.f : 0.f;
                    v *= (1.f - sp);
                    outp[(size_t)(t * M2_ + row) * Nloc + lc] = (bf16)sp;
                }
                if (suspect) {
                    int ccol = n0 + wn * 32 + ni * 16 + m16;
                    unsigned idx = atomicAdd(susp, 1u);
                    if (idx < SUSP_CAP) susp[1 + idx] = (unsigned)(row * 2048 + ccol);
                }
            }
}

// ---------------------------------------------------------------------------
// Kernel 2b: fp64 fixup of suspect trajectories. One wave per suspect.
// ---------------------------------------------------------------------------
__global__ __launch_bounds__(256) void fixup_kernel(
    const bf16* __restrict__ xs, const float* __restrict__ q_w,
    const float* __restrict__ k_w, const float* __restrict__ v_w,
    bf16* __restrict__ q_sp, bf16* __restrict__ k_sp, bf16* __restrict__ v_sp,
    const unsigned* __restrict__ susp)
{
    unsigned count = susp[0];
    if (count > SUSP_CAP) count = SUSP_CAP;
    const int lane = threadIdx.x & 63;
    const int wid  = (blockIdx.x * blockDim.x + threadIdx.x) >> 6;
    const int nw   = (gridDim.x * blockDim.x) >> 6;
    for (unsigned i = wid; i < count; i += nw) {
        unsigned e = susp[1 + i];
        int row = e >> 11, col = e & 2047;
        const float* W; bf16* outp; int Nloc, lc;
        if (col < 768)      { W = q_w + (size_t)col * D_;         outp = q_sp; Nloc = 768; lc = col; }
        else if (col < 960) { W = k_w + (size_t)(col - 768) * D_; outp = k_sp; Nloc = 192; lc = col - 768; }
        else                { W = v_w + (size_t)(col - 960) * D_; outp = v_sp; Nloc = 192; lc = col - 960; }
        double v = 0.0;
        for (int t = 0; t < T_; ++t) {
            const bf16* ar = xs + (size_t)(t * M2_ + row) * D_;
            double y = 0.0;
            for (int k = lane; k < D_; k += 64)
                y += (double)(float)ar[k] * (double)W[k];
            #pragma unroll
            for (int off = 1; off < 64; off <<= 1)
                y += __shfl_xor(y, off);
            v = v * 0.5 + y;
            unsigned sp = (v >= 1.0) ? 1u : 0u;
            if (lane == 0) outp[(size_t)(t * M2_ + row) * Nloc + lc] = (bf16)(float)sp;
            if (sp) v = 0.0;
        }
    }
}

// ---------------------------------------------------------------------------
// Kernel 3: partial k^T v. Block (g, cc): c-range cc*128..+128. fp32 exact
// integer partials -> M_part[cc][g][96][96].
// ---------------------------------------------------------------------------
__global__ __launch_bounds__(256) void ktv_kernel(
    const bf16* __restrict__ k_sp, const bf16* __restrict__ v_sp,
    float* __restrict__ M_part)
{
    const int g    = blockIdx.x;
    const int cc   = blockIdx.y;
    const int kvh  = g % HL_;
    const int tb   = g / HL_;
    const int wave = threadIdx.x >> 6;
    const int lane = threadIdx.x & 63;
    const int m16  = lane & 15, quad = lane >> 4;

    __shared__ __align__(16) bf16 klds[96 * 40];
    __shared__ __align__(16) bf16 vlds[96 * 40];

    f32x4 acc[9];
    #pragma unroll
    for (int i = 0; i < 9; i++) { f32x4 z = {0.f,0.f,0.f,0.f}; acc[i] = z; }

    const bf16* kbase = k_sp + ((size_t)tb * C_ + cc * 128) * MKV_ + kvh * HD_;
    const bf16* vbase = v_sp + ((size_t)tb * C_ + cc * 128) * MKV_ + kvh * HD_;

    for (int c0 = 0; c0 < 128; c0 += 32) {
        __syncthreads();
        for (int idx = threadIdx.x; idx < 32 * 96; idx += 256) {
            int d = idx % 96;
            int c = idx / 96;
            klds[d * 40 + c] = kbase[(size_t)(c0 + c) * MKV_ + d];
            vlds[d * 40 + c] = vbase[(size_t)(c0 + c) * MKV_ + d];
        }
        __syncthreads();
        #pragma unroll
        for (int i = 0; i < 9; i++) {
            int tile = wave + i * 4;
            int mt = tile / 6, nt = tile % 6;
            bf16x8 a = *(const bf16x8*)(&klds[(mt * 16 + m16) * 40 + quad * 8]);
            bf16x8 b = *(const bf16x8*)(&vlds[(nt * 16 + m16) * 40 + quad * 8]);
            acc[i] = __builtin_amdgcn_mfma_f32_16x16x32_bf16(a, b, acc[i], 0, 0, 0);
        }
    }
    float* op = M_part + ((size_t)cc * 64 + g) * HD_ * HD_;
    #pragma unroll
    for (int i = 0; i < 9; i++) {
        int tile = wave + i * 4;
        int mt = tile / 6, nt = tile % 6;
        #pragma unroll
        for (int r = 0; r < 4; r++) {
            int d = mt * 16 + quad * 4 + r;
            int j = nt * 16 + m16;
            op[(size_t)j * HD_ + d] = acc[i][r];
        }
    }
}

// ---------------------------------------------------------------------------
// Kernel 3b: sum partials, split to exact hi/lo bf16.
// ---------------------------------------------------------------------------
__global__ __launch_bounds__(256) void cvtM_kernel(
    const float* __restrict__ M_part, bf16* __restrict__ M_hi,
    bf16* __restrict__ M_lo)
{
    int i = blockIdx.x * 256 + threadIdx.x;
    if (i >= 64 * HD_ * HD_) return;
    float m = M_part[i] + M_part[i + 589824] + M_part[i + 2 * 589824] + M_part[i + 3 * 589824];
    bf16 h = (bf16)m;
    M_hi[i] = h;
    M_lo[i] = (bf16)(m - (float)h);
}

// ---------------------------------------------------------------------------
// Kernel 4: out_attn = 0.1 * q @ M. Block (tbh, c128): M hi/lo staged once
// in padded LDS (row stride 104 elems -> conflict-free b128 reads).
// ---------------------------------------------------------------------------
__global__ __launch_bounds__(256) void qm_kernel(
    const bf16* __restrict__ q_sp, const bf16* __restrict__ M_hi,
    const bf16* __restrict__ M_lo, bf16* __restrict__ out_attn)
{
    const int tbh  = blockIdx.x;
    const int h    = tbh % H_;
    const int tb   = tbh / H_;
    const int g    = tb * HL_ + (h >> 2);
    const int wave = threadIdx.x >> 6;
    const int lane = threadIdx.x & 63;
    const int m16  = lane & 15, quad = lane >> 4;
    const int cw   = blockIdx.y * 128 + wave * 32;

    __shared__ __align__(16) bf16 Mh[96 * 104];
    __shared__ __align__(16) bf16 Ml[96 * 104];
    {   // stage M: 96 rows x 12 segs = 1152 chunks per array
        const bf16* gh = M_hi + (size_t)g * HD_ * HD_;
        const bf16* gl = M_lo + (size_t)g * HD_ * HD_;
        #pragma unroll
        for (int j = 0; j < 5; j++) {
            int ci = j * 256 + threadIdx.x;
            if (ci < 1152) {
                int row = ci / 12, seg = ci % 12;
                *(bf16x8*)&Mh[row * 104 + seg * 8] = *(const bf16x8*)(gh + row * HD_ + seg * 8);
                *(bf16x8*)&Ml[row * 104 + seg * 8] = *(const bf16x8*)(gl + row * HD_ + seg * 8);
            }
        }
    }
    __syncthreads();

    f32x4 acc[2][6];
    #pragma unroll
    for (int mi = 0; mi < 2; mi++)
        #pragma unroll
        for (int nt = 0; nt < 6; nt++) { f32x4 z = {0.f,0.f,0.f,0.f}; acc[mi][nt] = z; }

    #pragma unroll
    for (int ks = 0; ks < 3; ++ks) {
        bf16x8 a[2];
        #pragma unroll
        for (int mi = 0; mi < 2; mi++)
            a[mi] = *(const bf16x8*)(q_sp + ((size_t)(tb * C_ + cw + mi * 16 + m16)) * D_
                                     + h * HD_ + ks * 32 + quad * 8);
        #pragma unroll
        for (int nt = 0; nt < 6; ++nt) {
            bf16x8 bh = *(const bf16x8*)&Mh[(nt * 16 + m16) * 104 + ks * 32 + quad * 8];
            bf16x8 bl = *(const bf16x8*)&Ml[(nt * 16 + m16) * 104 + ks * 32 + quad * 8];
            #pragma unroll
            for (int mi = 0; mi < 2; mi++) {
                acc[mi][nt] = __builtin_amdgcn_mfma_f32_16x16x32_bf16(a[mi], bh, acc[mi][nt], 0, 0, 0);
                acc[mi][nt] = __builtin_amdgcn_mfma_f32_16x16x32_bf16(a[mi], bl, acc[mi][nt], 0, 0, 0);
            }
        }
    }
    #pragma unroll
    for (int mi = 0; mi < 2; mi++)
        #pragma unroll
        for (int nt = 0; nt < 6; nt++)
            #pragma unroll
            for (int r = 0; r < 4; r++) {
                int c = cw + mi * 16 + quad * 4 + r;
                int j = nt * 16 + m16;
                out_attn[((size_t)(tb * C_ + c)) * D_ + h * HD_ + j] = (bf16)(0.1f * acc[mi][nt][r]);
            }
}

// ---------------------------------------------------------------------------
// Kernel 5: final = out_attn @ wo^T. 128x128 tile, BK=64, XOR-swizzled LDS.
// ---------------------------------------------------------------------------
__global__ __launch_bounds__(256) void final_gemm_kernel(
    const bf16* __restrict__ A, const bf16* __restrict__ W, float* __restrict__ out)
{
    __shared__ __align__(16) bf16 Alds[128 * 64];   // 16 KB
    __shared__ __align__(16) bf16 Blds[128 * 64];   // 16 KB
    const int tid  = threadIdx.x;
    const int wave = tid >> 6, lane = tid & 63;
    const int m16  = lane & 15, quad = lane >> 4;
    const int wm   = wave >> 1, wn = wave & 1;
    const int m0   = blockIdx.x * 128, n0 = blockIdx.y * 128;

    f32x4 acc[4][4];
    #pragma unroll
    for (int a = 0; a < 4; a++)
        #pragma unroll
        for (int b = 0; b < 4; b++) { f32x4 z = {0.f,0.f,0.f,0.f}; acc[a][b] = z; }

    for (int k0 = 0; k0 < D_; k0 += 64) {
        __syncthreads();
        #pragma unroll
        for (int j = 0; j < 4; j++) {
            int ci = j * 256 + tid;
            int row = ci >> 3, slot = ci & 7;
            int seg = slot ^ ((row >> 1) & 7);
            gld16(A + (size_t)(m0 + row) * D_ + k0 + seg * 8, Alds + ci * 8);
            gld16(W + (size_t)(n0 + row) * D_ + k0 + seg * 8, Blds + ci * 8);
        }
        __syncthreads();
        #pragma unroll
        for (int kc = 0; kc < 2; kc++) {
            bf16x8 a[4], b[4];
            #pragma unroll
            for (int mi = 0; mi < 4; mi++) {
                int row = wm * 64 + mi * 16 + m16;
                a[mi] = *(const bf16x8*)&Alds[row * 64 + (((kc * 4 + quad) ^ ((row >> 1) & 7)) * 8)];
            }
            #pragma unroll
            for (int ni = 0; ni < 4; ni++) {
                int row = wn * 64 + ni * 16 + m16;
                b[ni] = *(const bf16x8*)&Blds[row * 64 + (((kc * 4 + quad) ^ ((row >> 1) & 7)) * 8)];
            }
            #pragma unroll
            for (int mi = 0; mi < 4; mi++)
                #pragma unroll
                for (int ni = 0; ni < 4; ni++)
                    acc[mi][ni] = __builtin_amdgcn_mfma_f32_16x16x32_bf16(a[mi], b[ni], acc[mi][ni], 0, 0, 0);
        }
    }
    #pragma unroll
    for (int mi = 0; mi < 4; mi++)
        #pragma unroll
        for (int ni = 0; ni < 4; ni++)
            #pragma unroll
            for (int r = 0; r < 4; r++) {
                int row = m0 + wm * 64 + mi * 16 + quad * 4 + r;
                int col = n0 + wn * 64 + ni * 16 + m16;
                out[(size_t)row * D_ + col] = acc[mi][ni][r];
            }
}

// ---------------------------------------------------------------------------
extern "C" void kernel_launch(void* const* d_in, const int* in_sizes, int n_in,
                              void* d_out, int out_size, void* d_ws, size_t ws_size,
                              hipStream_t stream) {
    const float* x    = (const float*)d_in[0];
    const float* q_w  = (const float*)d_in[1];
    const float* k_w  = (const float*)d_in[2];
    const float* v_w  = (const float*)d_in[3];
    const float* wo_w = (const float*)d_in[4];
    float* out = (float*)d_out;

    char* ws = (char*)d_ws;
    bf16* xs    = (bf16*)(ws);                  // 25,165,824  (T,M2,768)
    bf16* q_sp  = (bf16*)(ws + 25165824);       // 25,165,824  (T,M2,768)
    bf16* k_sp  = (bf16*)(ws + 50331648);       //  6,291,456  (T,M2,192)
    bf16* v_sp  = (bf16*)(ws + 56623104);       //  6,291,456  (T,M2,192)
    bf16* whi   = (bf16*)(ws + 62914560);       //  1,769,472  (1152,768)
    bf16* wlo   = (bf16*)(ws + 64684032);       //  1,769,472
    bf16* wo_bf = (bf16*)(ws + 66453504);       //  1,179,648
    bf16* M_hi  = (bf16*)(ws + 67633152);       //  1,179,648  (64,96,96)
    bf16* M_lo  = (bf16*)(ws + 68812800);       //  1,179,648
    unsigned* susp = (unsigned*)(ws + 69992448);//    262,148  (count + entries)
    bf16* out_attn = xs;                        // alias: xs dead after fixup
    float* M_part  = out;                       // d_out as scratch (9.4 MB of 50 MB)

    hipLaunchKernelGGL(prep_kernel, dim3(2048), dim3(256), 0, stream,
                       x, q_w, k_w, v_w, wo_w, xs, whi, wlo, wo_bf, susp);
    hipLaunchKernelGGL(proj_lif_kernel, dim3(M2_ / 64, NCOMB / 64), dim3(256), 0, stream,
                       xs, whi, wlo, q_sp, k_sp, v_sp, susp);
    hipLaunchKernelGGL(fixup_kernel, dim3(256), dim3(256), 0, stream,
                       xs, q_w, k_w, v_w, q_sp, k_sp, v_sp, susp);
    hipLaunchKernelGGL(ktv_kernel, dim3(T_ * B_ * HL_, 4), dim3(256), 0, stream,
                       k_sp, v_sp, M_part);
    hipLaunchKernelGGL(cvtM_kernel, dim3((64 * HD_ * HD_ + 255) / 256), dim3(256), 0, stream,
                       M_part, M_hi, M_lo);
    hipLaunchKernelGGL(qm_kernel, dim3(T_ * B_ * H_, C_ / 128), dim3(256), 0, stream,
                       q_sp, M_hi, M_lo, out_attn);
    hipLaunchKernelGGL(final_gemm_kernel, dim3(M3_ / 128, D_ / 128), dim3(256), 0, stream,
                       out_attn, wo_bf, out);
}